// Round 10
// baseline (305.221 us; speedup 1.0000x reference)
//
#include <hip/hip_runtime.h>
#include <hip/hip_bf16.h>

// GCN 2-layer + global_add_pool on MI355X.
// R16 = R15 with the TLP bug fixed: NPB 128 -> 32.
// R15 proved XCD slice-locality works (FETCH 82 -> 22.8 MB) but its grid
// (1568 blocks = 6272 waves) was BELOW chip residency (~8192 waves) ->
// occupancy 58%, latency exposed, 89 us. NPB=32 gives 6256 blocks =
// 25k waves (~3 residency generations) with identical per-edge code.

typedef _Float16 f16x8 __attribute__((ext_vector_type(8)));
typedef float f32x4 __attribute__((ext_vector_type(4)));

#define BCHUNK 4096
#define NPB 32   // nodes per node-block in agg kernels (R16: was 128)

static __device__ __forceinline__ float f16lo(unsigned int u) {
    union { unsigned short s; _Float16 h; } c; c.s = (unsigned short)(u & 0xffff);
    return (float)c.h;
}
static __device__ __forceinline__ float f16hi(unsigned int u) {
    union { unsigned short s; _Float16 h; } c; c.s = (unsigned short)(u >> 16);
    return (float)c.h;
}
static __device__ __forceinline__ unsigned int pack2f16(float x, float y) {
    union { unsigned short s; _Float16 h; } a, b;
    a.h = (_Float16)x; b.h = (_Float16)y;
    return (unsigned int)a.s | ((unsigned int)b.s << 16);
}

// ---------------- bin_hist + phase-0 init ----------------
__global__ __launch_bounds__(256) void bin_hist(const int* __restrict__ ei,
                                                const float* __restrict__ W1,
                                                _Float16* __restrict__ wfrag,
                                                float* __restrict__ P,
                                                _Float16* __restrict__ hb,
                                                _Float16* __restrict__ ob,
                                                int* __restrict__ counts,
                                                int E, int N, int NB, int NBLK) {
    __shared__ int hist[256];
    int t = threadIdx.x, blk = blockIdx.x;
    int gtid = blk * 256 + t;
    int gstride = gridDim.x * 256;
    int NP8 = N + 8;

    // phase 0: independent init (P, slice-major sentinel rows, wfrag)
    for (int i = gtid; i < 128 * 128; i += gstride) P[i] = 0.f;
    if (gtid < 64) {
        int s = gtid >> 4, j = gtid & 15;   // slice, u32-within-row
        ((unsigned int*)hb)[(size_t)s * NP8 * 16 + (size_t)N * 16 + j] = 0u;
        ((unsigned int*)ob)[(size_t)s * NP8 * 16 + (size_t)N * 16 + j] = 0u;
    }
    if (gtid < 2048) {
        int lane = gtid & 63, kc = (gtid >> 6) & 3, nb = gtid >> 8;
        int col = nb * 16 + (lane & 15);
        int krow = kc * 32 + (lane >> 4) * 8;
#pragma unroll
        for (int j = 0; j < 8; j++)
            wfrag[gtid * 8 + j] = (_Float16)W1[(krow + j) * 128 + col];
    }

    // bucket histogram
    for (int b = t; b < NB; b += 256) hist[b] = 0;
    __syncthreads();
    int base = blk * BCHUNK;
    int end = min(E, base + BCHUNK);
    for (int e = base + t; e < end; e += 256)
        atomicAdd(&hist[ei[E + e] >> 8], 1);
    __syncthreads();
    for (int b = t; b < NB; b += 256) counts[b * NBLK + blk] = hist[b];
}

// ---------------- per-bucket segmented scan of chunk counts ----------------
__global__ __launch_bounds__(256) void scan_counts_seg(int* __restrict__ counts,
                                                       int* __restrict__ btot,
                                                       int NBLK, int BCAP) {
    __shared__ int s[256];
    int b = blockIdx.x, t = threadIdx.x;
    int carry = 0;
    for (int base = 0; base < NBLK; base += 256) {
        int idx = base + t;
        int v = (idx < NBLK) ? counts[b * NBLK + idx] : 0;
        s[t] = v;
        __syncthreads();
        for (int off = 1; off < 256; off *= 2) {
            int u = (t >= off) ? s[t - off] : 0;
            __syncthreads();
            s[t] += u;
            __syncthreads();
        }
        int excl = s[t] - v + carry;
        if (idx < NBLK) counts[b * NBLK + idx] = b * BCAP + excl;
        carry += s[255];
        __syncthreads();
    }
    if (t == 0) btot[b] = carry;
}

// ---------------- bin_scatter ----------------
__global__ __launch_bounds__(256) void bin_scatter(const int* __restrict__ ei,
                                                   const int* __restrict__ counts,
                                                   unsigned int* __restrict__ bedges,
                                                   int E, int NB, int NBLK) {
    __shared__ int lcur[256];
    int t = threadIdx.x, blk = blockIdx.x;
    for (int b = t; b < NB; b += 256) lcur[b] = counts[b * NBLK + blk];
    __syncthreads();
    int base = blk * BCHUNK;
    int end = min(E, base + BCHUNK);
    for (int e = base + t; e < end; e += 256) {
        int s = ei[e];
        int d = ei[E + e];
        int pos = atomicAdd(&lcur[d >> 8], 1);
        bedges[pos] = (unsigned int)s | ((unsigned int)(d & 255) << 16);
    }
}

// ---------------- build_csr ----------------
__global__ __launch_bounds__(256) void build_csr(const unsigned int* __restrict__ bedges,
                                                 const int* __restrict__ btot,
                                                 int* __restrict__ cnt,
                                                 int* __restrict__ row_start,
                                                 float* __restrict__ dinv,
                                                 int* __restrict__ srcs,
                                                 int N, int BCAP, int SCAP) {
    __shared__ int lcnt[256];
    __shared__ int lpre[256];
    __shared__ int lcur[256];
    int b = blockIdx.x, t = threadIdx.x;
    int node = (b << 8) + t;
    lcnt[t] = 0;
    __syncthreads();
    int bstart = b * BCAP;
    int bend = bstart + btot[b];
    for (int i = bstart + t; i < bend; i += 256)
        atomicAdd(&lcnt[bedges[i] >> 16], 1);
    __syncthreads();
    int c = lcnt[t];
    int pc = (c + 7) & ~7;
    lpre[t] = pc;
    __syncthreads();
    for (int off = 1; off < 256; off *= 2) {
        int u = (t >= off) ? lpre[t - off] : 0;
        __syncthreads();
        lpre[t] += u;
        __syncthreads();
    }
    int rs = b * SCAP + lpre[t] - pc;
    if (node < N) {
        row_start[node] = rs;
        cnt[node] = c;
        dinv[node] = rsqrtf((float)c + 1.0f);
    }
    lcur[t] = rs;
    __syncthreads();
    for (int i = bstart + t; i < bend; i += 256) {
        unsigned int p = bedges[i];
        int pos = atomicAdd(&lcur[p >> 16], 1);
        srcs[pos] = (int)(p & 0xffffu);
    }
    if (node < N) {
        for (int j = rs + c; j < rs + pc; j++) srcs[j] = N;  // sentinel zero row
    }
}

// ---------------- GEMM: slice-major C = dinv[row] * (A @ W) ----------------
__global__ __launch_bounds__(256) void gemm_mfma_f32in(const float* __restrict__ A,
                                                       const _Float16* __restrict__ wfrag,
                                                       const float* __restrict__ dinv,
                                                       _Float16* __restrict__ C,
                                                       int M, int NP8) {
    __shared__ _Float16 As[128 * 136];
    int t = threadIdx.x;
    int row0 = blockIdx.x * 128;

    const float4* A4 = (const float4*)A;
#pragma unroll
    for (int it = 0; it < 16; it++) {
        int v = it * 256 + t;
        int row = v >> 5;
        int seg = v & 31;
        float4 val = make_float4(0.f, 0.f, 0.f, 0.f);
        if (row0 + row < M) val = A4[(size_t)(row0 + row) * 32 + seg];
        _Float16* pp = &As[row * 136 + seg * 4];
        pp[0] = (_Float16)val.x; pp[1] = (_Float16)val.y;
        pp[2] = (_Float16)val.z; pp[3] = (_Float16)val.w;
    }
    __syncthreads();

    int wv = t >> 6;
    int lane = t & 63;
    int lrow = lane & 15;
    int lq = lane >> 4;

    f32x4 acc[2][8];
#pragma unroll
    for (int i = 0; i < 2; i++)
#pragma unroll
        for (int j = 0; j < 8; j++) acc[i][j] = (f32x4){0.f, 0.f, 0.f, 0.f};

#pragma unroll
    for (int kc = 0; kc < 4; kc++) {
        int k0 = kc * 32;
        f16x8 a0 = *((const f16x8*)&As[(wv * 32 + lrow) * 136 + k0 + lq * 8]);
        f16x8 a1 = *((const f16x8*)&As[(wv * 32 + 16 + lrow) * 136 + k0 + lq * 8]);
#pragma unroll
        for (int nb = 0; nb < 8; nb++) {
            f16x8 b = ((const f16x8*)wfrag)[(nb * 4 + kc) * 64 + lane];
            acc[0][nb] = __builtin_amdgcn_mfma_f32_16x16x32_f16(a0, b, acc[0][nb], 0, 0, 0);
            acc[1][nb] = __builtin_amdgcn_mfma_f32_16x16x32_f16(a1, b, acc[1][nb], 0, 0, 0);
        }
    }

#pragma unroll
    for (int ti = 0; ti < 2; ti++) {
#pragma unroll
        for (int r = 0; r < 4; r++) {
            int row = row0 + wv * 32 + ti * 16 + lq * 4 + r;
            if (row < M) {
                float dv = dinv[row];
#pragma unroll
                for (int nb = 0; nb < 8; nb++) {
                    int slice = nb >> 1;
                    C[(size_t)slice * NP8 * 32 + (size_t)row * 32 + (nb & 1) * 16 + lrow] =
                        (_Float16)(acc[ti][nb][r] * dv);
                }
            }
        }
    }
}

// ---------------- agg1 (XCD-sliced): o = relu(dn*(sum+self)+b1); ob = dn*o ----------------
__global__ __launch_bounds__(256) void agg1(const _Float16* __restrict__ hb,
                                            const int* __restrict__ srcs,
                                            const int* __restrict__ row_start,
                                            const int* __restrict__ cnt,
                                            const float* __restrict__ dinv,
                                            const float* __restrict__ bias,
                                            _Float16* __restrict__ ob,
                                            int n, int NBLKS, int NP8) {
    int xcd = blockIdx.x & 7;
    int slice = xcd >> 1;
    int nb = (blockIdx.x >> 3) * 2 + (xcd & 1);
    if (nb >= NBLKS) return;
    int wv = threadIdx.x >> 6, lane = threadIdx.x & 63;
    int eg = lane >> 3, c8 = lane & 7;
    const uint2* h2 = (const uint2*)hb + (size_t)slice * NP8 * 8;  // row stride 8 uint2
    uint2* obs = (uint2*)ob + (size_t)slice * NP8 * 8;
    float4 bv = ((const float4*)bias)[slice * 8 + c8];
    int base = nb * NPB;
    for (int i = wv; i < NPB; i += 4) {
        int node = base + i;
        if (node >= n) break;
        int s0 = row_start[node];
        int c = cnt[node];
        int nit = (c + 7) >> 3;
        float dn = dinv[node];
        const int* sp = srcs + s0;
        float a0 = 0.f, a1 = 0.f, a2 = 0.f, a3 = 0.f;
        int spre = (nit > 0) ? sp[eg] : 0;
        for (int it = 0; it < nit; it++) {
            int scur = spre;
            int nxt = (it + 1 < nit) ? it + 1 : it;
            spre = sp[nxt * 8 + eg];
            uint2 v = h2[(size_t)(unsigned)scur * 8 + c8];
            a0 += f16lo(v.x); a1 += f16hi(v.x);
            a2 += f16lo(v.y); a3 += f16hi(v.y);
        }
#pragma unroll
        for (int off = 8; off <= 32; off <<= 1) {
            a0 += __shfl_xor(a0, off); a1 += __shfl_xor(a1, off);
            a2 += __shfl_xor(a2, off); a3 += __shfl_xor(a3, off);
        }
        uint2 hs = h2[(size_t)node * 8 + c8];
        float o0 = fmaxf(fmaf(dn, a0 + f16lo(hs.x), bv.x), 0.f) * dn;
        float o1 = fmaxf(fmaf(dn, a1 + f16hi(hs.x), bv.y), 0.f) * dn;
        float o2 = fmaxf(fmaf(dn, a2 + f16lo(hs.y), bv.z), 0.f) * dn;
        float o3 = fmaxf(fmaf(dn, a3 + f16hi(hs.y), bv.w), 0.f) * dn;
        if (eg == 0) {
            uint2 w;
            w.x = pack2f16(o0, o1);
            w.y = pack2f16(o2, o3);
            obs[(size_t)node * 8 + c8] = w;
        }
    }
}

// ---------------- agg2 + pool (XCD-sliced, register pool accumulator) ----------------
__global__ __launch_bounds__(256) void agg2_pool(const _Float16* __restrict__ ob,
                                                 const int* __restrict__ srcs,
                                                 const int* __restrict__ row_start,
                                                 const int* __restrict__ cnt,
                                                 const float* __restrict__ dinv,
                                                 const int* __restrict__ batch,
                                                 float* __restrict__ P,
                                                 int n, int NBLKS, int NP8) {
    int xcd = blockIdx.x & 7;
    int slice = xcd >> 1;
    int nb = (blockIdx.x >> 3) * 2 + (xcd & 1);
    if (nb >= NBLKS) return;
    int wv = threadIdx.x >> 6, lane = threadIdx.x & 63;
    int eg = lane >> 3, c8 = lane & 7;
    const uint2* h2 = (const uint2*)ob + (size_t)slice * NP8 * 8;
    int colb = slice * 32 + c8 * 4;
    int base = nb * NPB;
    float p0 = 0.f, p1 = 0.f, p2 = 0.f, p3 = 0.f;
    int gcur = -1;
    for (int i = wv; i < NPB; i += 4) {
        int node = base + i;
        if (node >= n) break;
        int g = batch[node];
        if (g != gcur) {
            if (gcur >= 0 && eg == 0) {
                atomicAdd(&P[gcur * 128 + colb + 0], p0);
                atomicAdd(&P[gcur * 128 + colb + 1], p1);
                atomicAdd(&P[gcur * 128 + colb + 2], p2);
                atomicAdd(&P[gcur * 128 + colb + 3], p3);
            }
            gcur = g;
            p0 = p1 = p2 = p3 = 0.f;
        }
        int s0 = row_start[node];
        int c = cnt[node];
        int nit = (c + 7) >> 3;
        float dn = dinv[node];
        const int* sp = srcs + s0;
        float a0 = 0.f, a1 = 0.f, a2 = 0.f, a3 = 0.f;
        int spre = (nit > 0) ? sp[eg] : 0;
        for (int it = 0; it < nit; it++) {
            int scur = spre;
            int nxt = (it + 1 < nit) ? it + 1 : it;
            spre = sp[nxt * 8 + eg];
            uint2 v = h2[(size_t)(unsigned)scur * 8 + c8];
            a0 += f16lo(v.x); a1 += f16hi(v.x);
            a2 += f16lo(v.y); a3 += f16hi(v.y);
        }
#pragma unroll
        for (int off = 8; off <= 32; off <<= 1) {
            a0 += __shfl_xor(a0, off); a1 += __shfl_xor(a1, off);
            a2 += __shfl_xor(a2, off); a3 += __shfl_xor(a3, off);
        }
        uint2 hs = h2[(size_t)node * 8 + c8];
        p0 += dn * (a0 + f16lo(hs.x));
        p1 += dn * (a1 + f16hi(hs.x));
        p2 += dn * (a2 + f16lo(hs.y));
        p3 += dn * (a3 + f16hi(hs.y));
    }
    if (gcur >= 0 && eg == 0) {
        atomicAdd(&P[gcur * 128 + colb + 0], p0);
        atomicAdd(&P[gcur * 128 + colb + 1], p1);
        atomicAdd(&P[gcur * 128 + colb + 2], p2);
        atomicAdd(&P[gcur * 128 + colb + 3], p3);
    }
}

// ---------------- out = P @ W2 + n_g * b2 ----------------
__global__ __launch_bounds__(128) void gemm_small(const float* __restrict__ P,
                                                  const float* __restrict__ W2,
                                                  const float* __restrict__ b2,
                                                  const int* __restrict__ batch,
                                                  float* __restrict__ out, int n) {
    __shared__ float prow[128];
    int g = blockIdx.x;
    int c = threadIdx.x;
    prow[c] = P[g * 128 + c];
    __syncthreads();
    int lo = 0, hi = n;
    while (lo < hi) { int mid = (lo + hi) >> 1; if (batch[mid] < g) lo = mid + 1; else hi = mid; }
    int start = lo;
    hi = n;
    while (lo < hi) { int mid = (lo + hi) >> 1; if (batch[mid] < g + 1) lo = mid + 1; else hi = mid; }
    float ng = (float)(lo - start);
    float acc = 0.f;
#pragma unroll 8
    for (int k = 0; k < 128; k++) acc = fmaf(prow[k], W2[k * 128 + c], acc);
    out[g * 128 + c] = acc + ng * b2[c];
}

extern "C" void kernel_launch(void* const* d_in, const int* in_sizes, int n_in,
                              void* d_out, int out_size, void* d_ws, size_t ws_size,
                              hipStream_t stream) {
    const float* x  = (const float*)d_in[0];
    const int*   ei = (const int*)d_in[1];
    const int*   batch = (const int*)d_in[2];
    const float* W1 = (const float*)d_in[3];
    const float* b1 = (const float*)d_in[4];
    const float* W2 = (const float*)d_in[5];
    const float* b2 = (const float*)d_in[6];
    float* out = (float*)d_out;

    const int N = in_sizes[2];       // 50000 (assumed <= 65536)
    const int E = in_sizes[1] / 2;   // 800000
    const int G = out_size / 128;    // element count -> 128 graphs
    const int NP8 = N + 8;

    const int NB = (N + 255) >> 8;              // 196 buckets
    const int NBLK = (E + BCHUNK - 1) / BCHUNK; // 196 chunks
    const int ncounts = NB * NBLK;
    const int BCAP = 8192;                      // per-bucket edge window
    const int SCAP = BCAP + 2048;               // per-bucket srcs window (pad8)

    // workspace layout (hb/ob slice-major: 4 x NP8 x 32 halves; row N zero)
    _Float16* hb = (_Float16*)d_ws;                  // NP8*128 halves
    _Float16* ob = hb + (size_t)NP8 * 128;           // NP8*128 halves
    int* cnt  = (int*)(ob + (size_t)NP8 * 128);      // N
    int* row_start = cnt + N;                        // N
    float* dinv    = (float*)(row_start + N);        // N
    int* srcs      = (int*)(dinv + N);               // NB*SCAP
    unsigned int* bedges = (unsigned int*)(srcs + (size_t)NB * SCAP); // NB*BCAP
    int* counts    = (int*)(bedges + (size_t)NB * BCAP); // NB*NBLK
    int* btot      = counts + ncounts;               // NB
    _Float16* wfrag1 = (_Float16*)(btot + NB);       // 128*128
    float* P       = (float*)(wfrag1 + 128 * 128);   // 128*128 f32

    const int NBLKS = (N + NPB - 1) / NPB;           // node-blocks for aggs
    const int AGRID = 8 * ((NBLKS + 1) / 2);         // 8 XCD-ids x pair index

    bin_hist<<<NBLK, 256, 0, stream>>>(ei, W1, wfrag1, P, hb, ob, counts, E, N, NB, NBLK);
    scan_counts_seg<<<NB, 256, 0, stream>>>(counts, btot, NBLK, BCAP);
    bin_scatter<<<NBLK, 256, 0, stream>>>(ei, counts, bedges, E, NB, NBLK);
    build_csr<<<NB, 256, 0, stream>>>(bedges, btot, cnt, row_start, dinv, srcs, N, BCAP, SCAP);

    gemm_mfma_f32in<<<(N + 127) / 128, 256, 0, stream>>>(x, wfrag1, dinv, hb, N, NP8);
    agg1<<<AGRID, 256, 0, stream>>>(hb, srcs, row_start, cnt, dinv, b1, ob, N, NBLKS, NP8);
    agg2_pool<<<AGRID, 256, 0, stream>>>(ob, srcs, row_start, cnt, dinv, batch, P, N, NBLKS, NP8);
    gemm_small<<<G, 128, 0, stream>>>(P, W2, b2, batch, out, N);
}

// Round 12
// 207.815 us; speedup vs baseline: 1.4687x; 1.4687x over previous
//
#include <hip/hip_runtime.h>
#include <hip/hip_bf16.h>

// GCN 2-layer + global_add_pool on MI355X.
// R18 = R17 resubmitted verbatim (container failure was infra-pattern:
// no novel sync in this kernel — ordinary launches only, audited clean).
// Change under test vs R14 (best 217.6 us): agg kernels process 2 nodes
// per wave with interleaved gather loops -> 4 independent f16x8 gathers
// in flight (2x R14's MLP). If this nulls, the line-request-throughput
// floor is confirmed 3 independent ways (R11 shape, R15/16 locality, R17 MLP).

typedef _Float16 f16x8 __attribute__((ext_vector_type(8)));
typedef float f32x4 __attribute__((ext_vector_type(4)));

#define BCHUNK 4096

static __device__ __forceinline__ unsigned int pack2f16(float x, float y) {
    union { unsigned short s; _Float16 h; } a, b;
    a.h = (_Float16)x; b.h = (_Float16)y;
    return (unsigned int)a.s | ((unsigned int)b.s << 16);
}

// ---------------- bin_hist + phase-0 init ----------------
__global__ __launch_bounds__(256) void bin_hist(const int* __restrict__ ei,
                                                const float* __restrict__ W1,
                                                _Float16* __restrict__ wfrag,
                                                float* __restrict__ P,
                                                _Float16* __restrict__ hb,
                                                _Float16* __restrict__ ob,
                                                int* __restrict__ counts,
                                                int E, int N, int NB, int NBLK) {
    __shared__ int hist[256];
    int t = threadIdx.x, blk = blockIdx.x;
    int gtid = blk * 256 + t;
    int gstride = gridDim.x * 256;

    // phase 0: independent init (P, sentinel rows, wfrag) — no grid deps
    for (int i = gtid; i < 128 * 128; i += gstride) P[i] = 0.f;
    if (gtid < 64) {
        ((unsigned int*)(hb + (size_t)N * 128))[gtid] = 0u;
        ((unsigned int*)(ob + (size_t)N * 128))[gtid] = 0u;
    }
    if (gtid < 2048) {
        int lane = gtid & 63, kc = (gtid >> 6) & 3, nb = gtid >> 8;
        int col = nb * 16 + (lane & 15);
        int krow = kc * 32 + (lane >> 4) * 8;
#pragma unroll
        for (int j = 0; j < 8; j++)
            wfrag[gtid * 8 + j] = (_Float16)W1[(krow + j) * 128 + col];
    }

    // bucket histogram
    for (int b = t; b < NB; b += 256) hist[b] = 0;
    __syncthreads();
    int base = blk * BCHUNK;
    int end = min(E, base + BCHUNK);
    for (int e = base + t; e < end; e += 256)
        atomicAdd(&hist[ei[E + e] >> 8], 1);
    __syncthreads();
    for (int b = t; b < NB; b += 256) counts[b * NBLK + blk] = hist[b];
}

// ---------------- per-bucket segmented scan of chunk counts ----------------
__global__ __launch_bounds__(256) void scan_counts_seg(int* __restrict__ counts,
                                                       int* __restrict__ btot,
                                                       int NBLK, int BCAP) {
    __shared__ int s[256];
    int b = blockIdx.x, t = threadIdx.x;
    int carry = 0;
    for (int base = 0; base < NBLK; base += 256) {
        int idx = base + t;
        int v = (idx < NBLK) ? counts[b * NBLK + idx] : 0;
        s[t] = v;
        __syncthreads();
        for (int off = 1; off < 256; off *= 2) {
            int u = (t >= off) ? s[t - off] : 0;
            __syncthreads();
            s[t] += u;
            __syncthreads();
        }
        int excl = s[t] - v + carry;
        if (idx < NBLK) counts[b * NBLK + idx] = b * BCAP + excl;
        carry += s[255];
        __syncthreads();
    }
    if (t == 0) btot[b] = carry;
}

// ---------------- bin_scatter ----------------
__global__ __launch_bounds__(256) void bin_scatter(const int* __restrict__ ei,
                                                   const int* __restrict__ counts,
                                                   unsigned int* __restrict__ bedges,
                                                   int E, int NB, int NBLK) {
    __shared__ int lcur[256];
    int t = threadIdx.x, blk = blockIdx.x;
    for (int b = t; b < NB; b += 256) lcur[b] = counts[b * NBLK + blk];
    __syncthreads();
    int base = blk * BCHUNK;
    int end = min(E, base + BCHUNK);
    for (int e = base + t; e < end; e += 256) {
        int s = ei[e];
        int d = ei[E + e];
        int pos = atomicAdd(&lcur[d >> 8], 1);
        bedges[pos] = (unsigned int)s | ((unsigned int)(d & 255) << 16);
    }
}

// ---------------- build_csr ----------------
__global__ __launch_bounds__(256) void build_csr(const unsigned int* __restrict__ bedges,
                                                 const int* __restrict__ btot,
                                                 int* __restrict__ cnt,
                                                 int* __restrict__ row_start,
                                                 float* __restrict__ dinv,
                                                 int* __restrict__ srcs,
                                                 int N, int BCAP, int SCAP) {
    __shared__ int lcnt[256];
    __shared__ int lpre[256];
    __shared__ int lcur[256];
    int b = blockIdx.x, t = threadIdx.x;
    int node = (b << 8) + t;
    lcnt[t] = 0;
    __syncthreads();
    int bstart = b * BCAP;
    int bend = bstart + btot[b];
    for (int i = bstart + t; i < bend; i += 256)
        atomicAdd(&lcnt[bedges[i] >> 16], 1);
    __syncthreads();
    int c = lcnt[t];
    int pc = (c + 7) & ~7;
    lpre[t] = pc;
    __syncthreads();
    for (int off = 1; off < 256; off *= 2) {
        int u = (t >= off) ? lpre[t - off] : 0;
        __syncthreads();
        lpre[t] += u;
        __syncthreads();
    }
    int rs = b * SCAP + lpre[t] - pc;
    if (node < N) {
        row_start[node] = rs;
        cnt[node] = c;
        dinv[node] = rsqrtf((float)c + 1.0f);
    }
    lcur[t] = rs;
    __syncthreads();
    for (int i = bstart + t; i < bend; i += 256) {
        unsigned int p = bedges[i];
        int pos = atomicAdd(&lcur[p >> 16], 1);
        srcs[pos] = (int)(p & 0xffffu);
    }
    if (node < N) {
        for (int j = rs + c; j < rs + pc; j++) srcs[j] = N;  // sentinel zero row
    }
}

// ---------------- GEMM: C = dinv[row] * (A @ W), fp16 MFMA ----------------
__global__ __launch_bounds__(256) void gemm_mfma_f32in(const float* __restrict__ A,
                                                       const _Float16* __restrict__ wfrag,
                                                       const float* __restrict__ dinv,
                                                       _Float16* __restrict__ C, int M) {
    __shared__ _Float16 As[128 * 136];
    int t = threadIdx.x;
    int row0 = blockIdx.x * 128;

    const float4* A4 = (const float4*)A;
#pragma unroll
    for (int it = 0; it < 16; it++) {
        int v = it * 256 + t;
        int row = v >> 5;
        int seg = v & 31;
        float4 val = make_float4(0.f, 0.f, 0.f, 0.f);
        if (row0 + row < M) val = A4[(size_t)(row0 + row) * 32 + seg];
        _Float16* pp = &As[row * 136 + seg * 4];
        pp[0] = (_Float16)val.x; pp[1] = (_Float16)val.y;
        pp[2] = (_Float16)val.z; pp[3] = (_Float16)val.w;
    }
    __syncthreads();

    int wv = t >> 6;
    int lane = t & 63;
    int lrow = lane & 15;
    int lq = lane >> 4;

    f32x4 acc[2][8];
#pragma unroll
    for (int i = 0; i < 2; i++)
#pragma unroll
        for (int j = 0; j < 8; j++) acc[i][j] = (f32x4){0.f, 0.f, 0.f, 0.f};

#pragma unroll
    for (int kc = 0; kc < 4; kc++) {
        int k0 = kc * 32;
        f16x8 a0 = *((const f16x8*)&As[(wv * 32 + lrow) * 136 + k0 + lq * 8]);
        f16x8 a1 = *((const f16x8*)&As[(wv * 32 + 16 + lrow) * 136 + k0 + lq * 8]);
#pragma unroll
        for (int nb = 0; nb < 8; nb++) {
            f16x8 b = ((const f16x8*)wfrag)[(nb * 4 + kc) * 64 + lane];
            acc[0][nb] = __builtin_amdgcn_mfma_f32_16x16x32_f16(a0, b, acc[0][nb], 0, 0, 0);
            acc[1][nb] = __builtin_amdgcn_mfma_f32_16x16x32_f16(a1, b, acc[1][nb], 0, 0, 0);
        }
    }

#pragma unroll
    for (int ti = 0; ti < 2; ti++) {
#pragma unroll
        for (int r = 0; r < 4; r++) {
            int row = row0 + wv * 32 + ti * 16 + lq * 4 + r;
            if (row < M) {
                float dv = dinv[row];
#pragma unroll
                for (int nb = 0; nb < 8; nb++)
                    C[(size_t)row * 128 + nb * 16 + lrow] = (_Float16)(acc[ti][nb][r] * dv);
            }
        }
    }
}

// ---------------- agg1: 2 nodes per wave, interleaved gather16 ----------------
__global__ __launch_bounds__(256) void agg1(const _Float16* __restrict__ hb,
                                            const int* __restrict__ srcs,
                                            const int* __restrict__ row_start,
                                            const int* __restrict__ cnt,
                                            const float* __restrict__ dinv,
                                            const float* __restrict__ bias,
                                            _Float16* __restrict__ ob, int n) {
    int wv = threadIdx.x >> 6, lane = threadIdx.x & 63;
    int cc = lane & 15, sg = lane >> 4;
    int nA = blockIdx.x * 8 + wv * 2;
    if (nA >= n) return;
    int nB = nA + 1;
    bool hasB = (nB < n);

    int nitA = (cnt[nA] + 7) >> 3;
    float dnA = dinv[nA];
    const int* spA = srcs + row_start[nA];
    int nitB = 0; float dnB = 0.f; const int* spB = spA;
    if (hasB) { nitB = (cnt[nB] + 7) >> 3; dnB = dinv[nB]; spB = srcs + row_start[nB]; }

    float accA[8], accB[8];
#pragma unroll
    for (int j = 0; j < 8; j++) { accA[j] = 0.f; accB[j] = 0.f; }

    int a0 = 0, a1 = 0, b0 = 0, b1 = 0;
    if (nitA > 0) { a0 = spA[sg]; a1 = spA[4 + sg]; }
    if (nitB > 0) { b0 = spB[sg]; b1 = spB[4 + sg]; }
    int itmax = max(nitA, nitB);
    for (int it = 0; it < itmax; it++) {
        if (it < nitA) {
            int c0 = a0, c1 = a1;
            int nx = (it + 1 < nitA) ? it + 1 : it;
            a0 = spA[nx * 8 + sg]; a1 = spA[nx * 8 + 4 + sg];
            f16x8 v0 = *((const f16x8*)&hb[(size_t)(unsigned)c0 * 128 + cc * 8]);
            f16x8 v1 = *((const f16x8*)&hb[(size_t)(unsigned)c1 * 128 + cc * 8]);
#pragma unroll
            for (int j = 0; j < 8; j++) accA[j] += (float)v0[j];
#pragma unroll
            for (int j = 0; j < 8; j++) accA[j] += (float)v1[j];
        }
        if (it < nitB) {
            int c0 = b0, c1 = b1;
            int nx = (it + 1 < nitB) ? it + 1 : it;
            b0 = spB[nx * 8 + sg]; b1 = spB[nx * 8 + 4 + sg];
            f16x8 v0 = *((const f16x8*)&hb[(size_t)(unsigned)c0 * 128 + cc * 8]);
            f16x8 v1 = *((const f16x8*)&hb[(size_t)(unsigned)c1 * 128 + cc * 8]);
#pragma unroll
            for (int j = 0; j < 8; j++) accB[j] += (float)v0[j];
#pragma unroll
            for (int j = 0; j < 8; j++) accB[j] += (float)v1[j];
        }
    }
#pragma unroll
    for (int j = 0; j < 8; j++) {
        accA[j] += __shfl_xor(accA[j], 16);
        accA[j] += __shfl_xor(accA[j], 32);
        accB[j] += __shfl_xor(accB[j], 16);
        accB[j] += __shfl_xor(accB[j], 32);
    }
    float4 q0 = ((const float4*)bias)[cc * 2];
    float4 q1 = ((const float4*)bias)[cc * 2 + 1];
    float bb[8] = {q0.x, q0.y, q0.z, q0.w, q1.x, q1.y, q1.z, q1.w};
    f16x8 hsA = *((const f16x8*)&hb[(size_t)nA * 128 + cc * 8]);
    f16x8 oA;
#pragma unroll
    for (int j = 0; j < 8; j++) {
        float tv = accA[j] + (float)hsA[j];
        oA[j] = (_Float16)(fmaxf(fmaf(dnA, tv, bb[j]), 0.f) * dnA);
    }
    if (sg == 0) *((f16x8*)&ob[(size_t)nA * 128 + cc * 8]) = oA;
    if (hasB) {
        f16x8 hsB = *((const f16x8*)&hb[(size_t)nB * 128 + cc * 8]);
        f16x8 oB;
#pragma unroll
        for (int j = 0; j < 8; j++) {
            float tv = accB[j] + (float)hsB[j];
            oB[j] = (_Float16)(fmaxf(fmaf(dnB, tv, bb[j]), 0.f) * dnB);
        }
        if (sg == 0) *((f16x8*)&ob[(size_t)nB * 128 + cc * 8]) = oB;
    }
}

// ---------------- agg2 + pool: 2 nodes per wave, interleaved ----------------
__global__ __launch_bounds__(256) void agg2_pool(const _Float16* __restrict__ ob,
                                                 const int* __restrict__ srcs,
                                                 const int* __restrict__ row_start,
                                                 const int* __restrict__ cnt,
                                                 const float* __restrict__ dinv,
                                                 const int* __restrict__ batch,
                                                 float* __restrict__ P, int n) {
    __shared__ float red[4][128];
    int wv = threadIdx.x >> 6, lane = threadIdx.x & 63;
    int cc = lane & 15, sg = lane >> 4;
    int base = blockIdx.x * 8;
    int nA = base + wv * 2;
    int nB = nA + 1;
    bool hasA = (nA < n), hasB = (nB < n);

    float accA[8], accB[8];
#pragma unroll
    for (int j = 0; j < 8; j++) { accA[j] = 0.f; accB[j] = 0.f; }
    int gA = -1, gB = -1;
    float dnA = 0.f, dnB = 0.f;

    if (hasA) {
        gA = batch[nA];
        dnA = dinv[nA];
        int nitA = (cnt[nA] + 7) >> 3;
        const int* spA = srcs + row_start[nA];
        int nitB = 0; const int* spB = spA;
        if (hasB) { gB = batch[nB]; dnB = dinv[nB]; nitB = (cnt[nB] + 7) >> 3; spB = srcs + row_start[nB]; }
        int a0 = 0, a1 = 0, b0 = 0, b1 = 0;
        if (nitA > 0) { a0 = spA[sg]; a1 = spA[4 + sg]; }
        if (nitB > 0) { b0 = spB[sg]; b1 = spB[4 + sg]; }
        int itmax = max(nitA, nitB);
        for (int it = 0; it < itmax; it++) {
            if (it < nitA) {
                int c0 = a0, c1 = a1;
                int nx = (it + 1 < nitA) ? it + 1 : it;
                a0 = spA[nx * 8 + sg]; a1 = spA[nx * 8 + 4 + sg];
                f16x8 v0 = *((const f16x8*)&ob[(size_t)(unsigned)c0 * 128 + cc * 8]);
                f16x8 v1 = *((const f16x8*)&ob[(size_t)(unsigned)c1 * 128 + cc * 8]);
#pragma unroll
                for (int j = 0; j < 8; j++) accA[j] += (float)v0[j];
#pragma unroll
                for (int j = 0; j < 8; j++) accA[j] += (float)v1[j];
            }
            if (it < nitB) {
                int c0 = b0, c1 = b1;
                int nx = (it + 1 < nitB) ? it + 1 : it;
                b0 = spB[nx * 8 + sg]; b1 = spB[nx * 8 + 4 + sg];
                f16x8 v0 = *((const f16x8*)&ob[(size_t)(unsigned)c0 * 128 + cc * 8]);
                f16x8 v1 = *((const f16x8*)&ob[(size_t)(unsigned)c1 * 128 + cc * 8]);
#pragma unroll
                for (int j = 0; j < 8; j++) accB[j] += (float)v0[j];
#pragma unroll
                for (int j = 0; j < 8; j++) accB[j] += (float)v1[j];
            }
        }
#pragma unroll
        for (int j = 0; j < 8; j++) {
            accA[j] += __shfl_xor(accA[j], 16);
            accA[j] += __shfl_xor(accA[j], 32);
            accB[j] += __shfl_xor(accB[j], 16);
            accB[j] += __shfl_xor(accB[j], 32);
        }
        f16x8 hsA = *((const f16x8*)&ob[(size_t)nA * 128 + cc * 8]);
#pragma unroll
        for (int j = 0; j < 8; j++) accA[j] = dnA * (accA[j] + (float)hsA[j]);
        if (hasB) {
            f16x8 hsB = *((const f16x8*)&ob[(size_t)nB * 128 + cc * 8]);
#pragma unroll
            for (int j = 0; j < 8; j++) accB[j] = dnB * (accB[j] + (float)hsB[j]);
        }
    }

    int lastn = min(base + 7, n - 1);
    bool uniform = (base < n) && (batch[base] == batch[lastn]) && (base + 7 < n);
    if (uniform) {
        if (sg == 0) {
#pragma unroll
            for (int j = 0; j < 8; j++) red[wv][cc * 8 + j] = accA[j] + accB[j];
        }
        __syncthreads();
        if (wv == 0) {
            int col = lane * 2;
            float sx = red[0][col] + red[1][col] + red[2][col] + red[3][col];
            float sy = red[0][col + 1] + red[1][col + 1] + red[2][col + 1] + red[3][col + 1];
            atomicAdd(&P[gA * 128 + col], sx);
            atomicAdd(&P[gA * 128 + col + 1], sy);
        }
    } else {
        if (hasA && sg == 0) {
            if (hasB && gB == gA) {
#pragma unroll
                for (int j = 0; j < 8; j++) atomicAdd(&P[gA * 128 + cc * 8 + j], accA[j] + accB[j]);
            } else {
#pragma unroll
                for (int j = 0; j < 8; j++) atomicAdd(&P[gA * 128 + cc * 8 + j], accA[j]);
                if (hasB) {
#pragma unroll
                    for (int j = 0; j < 8; j++) atomicAdd(&P[gB * 128 + cc * 8 + j], accB[j]);
                }
            }
        }
    }
}

// ---------------- out = P @ W2 + n_g * b2 ----------------
__global__ __launch_bounds__(128) void gemm_small(const float* __restrict__ P,
                                                  const float* __restrict__ W2,
                                                  const float* __restrict__ b2,
                                                  const int* __restrict__ batch,
                                                  float* __restrict__ out, int n) {
    __shared__ float prow[128];
    int g = blockIdx.x;
    int c = threadIdx.x;
    prow[c] = P[g * 128 + c];
    __syncthreads();
    int lo = 0, hi = n;
    while (lo < hi) { int mid = (lo + hi) >> 1; if (batch[mid] < g) lo = mid + 1; else hi = mid; }
    int start = lo;
    hi = n;
    while (lo < hi) { int mid = (lo + hi) >> 1; if (batch[mid] < g + 1) lo = mid + 1; else hi = mid; }
    float ng = (float)(lo - start);
    float acc = 0.f;
#pragma unroll 8
    for (int k = 0; k < 128; k++) acc = fmaf(prow[k], W2[k * 128 + c], acc);
    out[g * 128 + c] = acc + ng * b2[c];
}

extern "C" void kernel_launch(void* const* d_in, const int* in_sizes, int n_in,
                              void* d_out, int out_size, void* d_ws, size_t ws_size,
                              hipStream_t stream) {
    const float* x  = (const float*)d_in[0];
    const int*   ei = (const int*)d_in[1];
    const int*   batch = (const int*)d_in[2];
    const float* W1 = (const float*)d_in[3];
    const float* b1 = (const float*)d_in[4];
    const float* W2 = (const float*)d_in[5];
    const float* b2 = (const float*)d_in[6];
    float* out = (float*)d_out;

    const int N = in_sizes[2];       // 50000 (assumed <= 65536)
    const int E = in_sizes[1] / 2;   // 800000
    const int G = out_size / 128;    // element count -> 128 graphs

    const int NB = (N + 255) >> 8;              // 196 buckets
    const int NBLK = (E + BCHUNK - 1) / BCHUNK; // 196 chunks
    const int ncounts = NB * NBLK;
    const int BCAP = 8192;                      // per-bucket edge window
    const int SCAP = BCAP + 2048;               // per-bucket srcs window (pad8)

    // workspace layout (hb/ob have N+8 rows; row N is the sentinel zero row)
    _Float16* hb = (_Float16*)d_ws;                  // (N+8)*128 halves
    _Float16* ob = hb + (size_t)(N + 8) * 128;       // (N+8)*128 halves
    int* cnt  = (int*)(ob + (size_t)(N + 8) * 128);  // N
    int* row_start = cnt + N;                        // N
    float* dinv    = (float*)(row_start + N);        // N
    int* srcs      = (int*)(dinv + N);               // NB*SCAP
    unsigned int* bedges = (unsigned int*)(srcs + (size_t)NB * SCAP); // NB*BCAP
    int* counts    = (int*)(bedges + (size_t)NB * BCAP); // NB*NBLK
    int* btot      = counts + ncounts;               // NB
    _Float16* wfrag1 = (_Float16*)(btot + NB);       // 128*128
    float* P       = (float*)(wfrag1 + 128 * 128);   // 128*128 f32

    bin_hist<<<NBLK, 256, 0, stream>>>(ei, W1, wfrag1, P, hb, ob, counts, E, N, NB, NBLK);
    scan_counts_seg<<<NB, 256, 0, stream>>>(counts, btot, NBLK, BCAP);
    bin_scatter<<<NBLK, 256, 0, stream>>>(ei, counts, bedges, E, NB, NBLK);
    build_csr<<<NB, 256, 0, stream>>>(bedges, btot, cnt, row_start, dinv, srcs, N, BCAP, SCAP);

    gemm_mfma_f32in<<<(N + 127) / 128, 256, 0, stream>>>(x, wfrag1, dinv, hb, N);
    agg1<<<(N + 7) / 8, 256, 0, stream>>>(hb, srcs, row_start, cnt, dinv, b1, ob, N);
    agg2_pool<<<(N + 7) / 8, 256, 0, stream>>>(ob, srcs, row_start, cnt, dinv, batch, P, N);
    gemm_small<<<G, 128, 0, stream>>>(P, W2, b2, batch, out, N);
}